// Round 4
// baseline (178.928 us; speedup 1.0000x reference)
//
#include <hip/hip_runtime.h>

typedef unsigned short u16;
typedef unsigned int   u32;
typedef unsigned long long u64;
typedef short  short8 __attribute__((ext_vector_type(8)));
typedef float  f32x4  __attribute__((ext_vector_type(4)));
typedef float  f32x16 __attribute__((ext_vector_type(16)));
typedef u16    u16x4  __attribute__((ext_vector_type(4)));

__device__ __forceinline__ u16 f2b(float f) {
    u32 u = __float_as_uint(f);
    u32 r = (u + 0x7fffu + ((u >> 16) & 1u)) >> 16;  // RNE to bf16
    return (u16)r;
}

__device__ __forceinline__ u32 cvtpk(float a, float b) {
    u32 r;
    asm("v_cvt_pk_bf16_f32 %0, %1, %2" : "=v"(r) : "v"(a), "v"(b));
    return r;  // lo = bf16(a), hi = bf16(b)
}

__device__ __forceinline__ void gload_lds16(const void* g, void* l) {
    __builtin_amdgcn_global_load_lds(
        (const __attribute__((address_space(1))) u32*)g,
        (__attribute__((address_space(3))) u32*)l,
        16, 0, 0);
}

// ---------------- fp32 -> bf16 cast ----------------
__global__ void cvt_bf16(const float* __restrict__ src, u16* __restrict__ dst, int n4) {
    int i = blockIdx.x * blockDim.x + threadIdx.x;
    if (i >= n4) return;
    float4 v = ((const float4*)src)[i];
    u16x4 r = { f2b(v.x), f2b(v.y), f2b(v.z), f2b(v.w) };
    ((u16x4*)dst)[i] = r;
}

// ---------------- C = A @ B^T (A:[M,K], B:[N,K], bf16 in, fp32 acc) ----------------
// (round-2 verified version, verbatim)
__global__ __launch_bounds__(256) void gemm_bt(
    const u16* __restrict__ A, const u16* __restrict__ Bm,
    u16* __restrict__ Cb, float* __restrict__ Cf, const float* __restrict__ bias,
    int M, int N, int K)
{
    __shared__ __align__(16) u16 As[128*32];
    __shared__ __align__(16) u16 Bs[128*32];
    const int t = threadIdx.x;
    const int w = t >> 6, lane = t & 63;
    const int l15 = lane & 15, lg = lane >> 4;
    const int m0 = blockIdx.y * 128, n0 = blockIdx.x * 128;
    const int wr = w >> 1, wc = w & 1;
    f32x4 acc[4][4] = {};

    for (int kt = 0; kt < K; kt += 32) {
        #pragma unroll
        for (int j = 0; j < 2; ++j) {
            const int c   = j*256 + t;
            const int row = c >> 2, colb = (c & 3) * 8;
            gload_lds16(&A [(size_t)(m0+row)*K + kt + colb], &As[(size_t)(j*256 + w*64)*8]);
            gload_lds16(&Bm[(size_t)(n0+row)*K + kt + colb], &Bs[(size_t)(j*256 + w*64)*8]);
        }
        __syncthreads();
        short8 af[4], bfr[4];
        #pragma unroll
        for (int mi = 0; mi < 4; ++mi)
            af[mi] = *(const short8*)&As[(wr*64 + mi*16 + l15)*32 + lg*8];
        #pragma unroll
        for (int ni = 0; ni < 4; ++ni)
            bfr[ni] = *(const short8*)&Bs[(wc*64 + ni*16 + l15)*32 + lg*8];
        #pragma unroll
        for (int mi = 0; mi < 4; ++mi)
            #pragma unroll
            for (int ni = 0; ni < 4; ++ni)
                acc[mi][ni] = __builtin_amdgcn_mfma_f32_16x16x32_bf16(af[mi], bfr[ni], acc[mi][ni], 0, 0, 0);
        __syncthreads();
    }

    #pragma unroll
    for (int mi = 0; mi < 4; ++mi) {
        #pragma unroll
        for (int ni = 0; ni < 4; ++ni) {
            const int row = m0 + wr*64 + mi*16 + lg*4;
            const int col = n0 + wc*64 + ni*16 + l15;
            if (Cb) {
                #pragma unroll
                for (int r = 0; r < 4; ++r)
                    Cb[(size_t)(row+r)*N + col] = f2b(acc[mi][ni][r]);
            } else {
                const float bv = bias ? bias[col] : 0.f;
                #pragma unroll
                for (int r = 0; r < 4; ++r)
                    Cf[(size_t)(row+r)*N + col] = acc[mi][ni][r] + bv;
            }
        }
    }
}

// ---------------- fused masked flash attention (round-2 body), kv-split x2 ----------------
// grid 1024: half = bid>>9 handles kv [half*1024, half*1024+1024).
// Inner 512 blocks decoded exactly as round 2. Writes UNNORMALIZED partial O (bf16)
// + per-row (m, l) f32 to scratch; attn_merge combines the two halves.
__global__ __launch_bounds__(256) void attn_half(
    const u16* __restrict__ qkv,   // [B*N][3072] bf16
    const int* __restrict__ mask,  // [B*N]
    u16* __restrict__ pO0, u16* __restrict__ pO1,   // [65536*64] each
    float* __restrict__ pM, float* __restrict__ pL) // [2*65536] each
{
    __shared__ __align__(16) u16 Ks[64*64];   // [kv][d], chunk ^= kv&7
    __shared__ __align__(16) u16 Vt[64*64];   // [d][kv], chunk ^= (d^(d>>3))&7

    const int t = threadIdx.x, w = t >> 6, lane = t & 63;
    const int l31 = lane & 31, hi = lane >> 5;

    const int half  = blockIdx.x >> 9;
    const int inner = blockIdx.x & 511;
    const int wid = ((inner & 7) << 6) | (inner >> 3);   // XCD-contiguous
    const int qt = wid & 15, h = (wid >> 4) & 15, b = wid >> 8;
    const int q0 = qt * 128 + w * 32;
    const int kvbase = half * 1024, kvend = kvbase + 1024;

    const size_t qrow = (size_t)(b*2048 + q0 + l31);
    short8 qf[4];
    #pragma unroll
    for (int i = 0; i < 4; ++i)
        qf[i] = *(const short8*)&qkv[qrow*3072 + h*64 + i*16 + hi*8];
    const int mq = mask[b*2048 + q0 + l31];

    float m_run = -3e38f, l_run = 0.f;
    f32x16 oacc[2] = {};

    const int vrr = t >> 3, vc8 = t & 7;  // V stage role: rows vrr, vrr+32
    short8 vreg0 = *(const short8*)&qkv[(size_t)(b*2048 + kvbase +      vrr)*3072 + 2048 + h*64 + vc8*8];
    short8 vreg1 = *(const short8*)&qkv[(size_t)(b*2048 + kvbase + 32 + vrr)*3072 + 2048 + h*64 + vc8*8];

    for (int kv0 = kvbase; kv0 < kvend; kv0 += 64) {
        __syncthreads();   // previous tile's compute done; Ks/Vt writable
        // ---- V^T swizzled scalar writes (conflict-free) ----
        #pragma unroll
        for (int p = 0; p < 2; ++p) {
            const int kv = p*32 + vrr;
            const int kvhi = kv >> 3, kvlo = kv & 7;
            const short8 v = p ? vreg1 : vreg0;
            #pragma unroll
            for (int j = 0; j < 8; ++j)
                Vt[(vc8*8 + j)*64 + ((kvhi ^ ((j ^ vc8) & 7)) << 3) + kvlo] = (u16)v[j];
        }
        // ---- K stage: global_load_lds, source pre-swizzled (chunk ^ row&7) ----
        #pragma unroll
        for (int i = 0; i < 2; ++i) {
            const int row = w*16 + i*8 + (lane >> 3);
            const int sc  = (lane & 7) ^ (lane >> 3);
            gload_lds16(&qkv[(size_t)(b*2048 + kv0 + row)*3072 + 1024 + h*64 + sc*8],
                        &Ks[(w*16 + i*8)*64]);
        }
        const unsigned long long bal = __ballot(mask[b*2048 + kv0 + lane] != 0);
        const u32 mwA = (u32)bal, mwB = (u32)(bal >> 32);
        __syncthreads();   // staged data visible

        // prefetch next tile's V (hides HBM under compute)
        if (kv0 + 64 < kvend) {
            vreg0 = *(const short8*)&qkv[(size_t)(b*2048 + kv0+64 + vrr)*3072 + 2048 + h*64 + vc8*8];
            vreg1 = *(const short8*)&qkv[(size_t)(b*2048 + kv0+96 + vrr)*3072 + 2048 + h*64 + vc8*8];
        }

        // ---- S^T: two 32x32 subtiles, 4 k-steps each ----
        f32x16 st0 = {}, st1 = {};
        #pragma unroll
        for (int kd = 0; kd < 4; ++kd) {
            const int c = (2*kd + hi) ^ (l31 & 7);
            short8 kf0 = *(const short8*)&Ks[ l31      *64 + c*8];
            short8 kf1 = *(const short8*)&Ks[(32 + l31)*64 + c*8];
            st0 = __builtin_amdgcn_mfma_f32_32x32x16_bf16(kf0, qf[kd], st0, 0, 0, 0);
            st1 = __builtin_amdgcn_mfma_f32_32x32x16_bf16(kf1, qf[kd], st1, 0, 0, 0);
        }

        // ---- mask + scale ----
        const u32 km0 = (mq ? mwA : 0u) >> (hi*4);
        const u32 km1 = (mq ? mwB : 0u) >> (hi*4);
        #pragma unroll
        for (int r = 0; r < 16; ++r) {
            const int pat = (r & 3) + 8*(r >> 2);
            const float t0 = ((km0 >> pat) & 1u) ? 0.f : -3e38f;
            const float t1 = ((km1 >> pat) & 1u) ? 0.f : -3e38f;
            st0[r] = fmaf(st0[r], 0.125f, t0);
            st1[r] = fmaf(st1[r], 0.125f, t1);
        }

        // ---- online softmax (stats at lane q = lane&31, replicated across hi) ----
        float pm0 = -3e38f, pm1 = -3e38f, pm2 = -3e38f, pm3 = -3e38f;
        #pragma unroll
        for (int r = 0; r < 16; r += 4) {
            pm0 = fmaxf(pm0, fmaxf(st0[r],   st1[r]));
            pm1 = fmaxf(pm1, fmaxf(st0[r+1], st1[r+1]));
            pm2 = fmaxf(pm2, fmaxf(st0[r+2], st1[r+2]));
            pm3 = fmaxf(pm3, fmaxf(st0[r+3], st1[r+3]));
        }
        float pm = fmaxf(fmaxf(pm0, pm1), fmaxf(pm2, pm3));
        pm = fmaxf(pm, __shfl_xor(pm, 32));
        const float m_new = fmaxf(m_run, pm);
        const float alpha = __expf(m_run - m_new);
        float rs0 = 0.f, rs1 = 0.f;
        #pragma unroll
        for (int r = 0; r < 16; ++r) {
            const float p0 = __expf(st0[r] - m_new);
            const float p1 = __expf(st1[r] - m_new);
            st0[r] = p0; st1[r] = p1;
            rs0 += p0; rs1 += p1;
        }
        float rs = rs0 + rs1;
        rs += __shfl_xor(rs, 32);
        l_run = l_run * alpha + rs;
        m_run = m_new;

        // ---- pack P to bf16 pairs, swap halves (in-register) ----
        u32 o_[16], x_[16];
        #pragma unroll
        for (int m = 0; m < 8; ++m) {
            o_[m]     = cvtpk(st0[2*m], st0[2*m+1]);
            o_[8 + m] = cvtpk(st1[2*m], st1[2*m+1]);
        }
        #pragma unroll
        for (int m = 0; m < 16; ++m) x_[m] = (u32)__shfl_xor((int)o_[m], 32);

        // ---- rescale O ----
        #pragma unroll
        for (int r = 0; r < 16; ++r) {
            const int pat = (r & 3) + 8*(r >> 2);
            const float ar = __shfl(alpha, pat + 4*hi);
            oacc[0][r] *= ar; oacc[1][r] *= ar;
        }

        // ---- PV: O += P @ V ----
        #pragma unroll
        for (int kk = 0; kk < 4; ++kk) {
            const int s8 = (kk >> 1) * 8, q4 = (kk & 1) * 4;
            union { u32 u[4]; short8 s; } pa;
            pa.u[0] = hi ? x_[s8+q4+2] : o_[s8+q4];
            pa.u[1] = hi ? x_[s8+q4+3] : o_[s8+q4+1];
            pa.u[2] = hi ? o_[s8+q4+2] : x_[s8+q4];
            pa.u[3] = hi ? o_[s8+q4+3] : x_[s8+q4+1];
            #pragma unroll
            for (int dt = 0; dt < 2; ++dt) {
                const int d = dt*32 + l31;
                const int c = (2*kk + hi) ^ ((d ^ (d >> 3)) & 7);
                short8 vf = *(const short8*)&Vt[d*64 + c*8];
                oacc[dt] = __builtin_amdgcn_mfma_f32_32x32x16_bf16(pa.s, vf, oacc[dt], 0, 0, 0);
            }
        }
    }

    // ---- epilogue: UNNORMALIZED partial O + (m, l) ----
    u16* __restrict__ pO = half ? pO1 : pO0;
    if (hi == 0) {
        const int rid = (b*2048 + q0 + l31)*16 + h;
        pM[half*65536 + rid] = m_run;
        pL[half*65536 + rid] = l_run;
    }
    #pragma unroll
    for (int r = 0; r < 16; ++r) {
        const int pat = (r & 3) + 8*(r >> 2);
        const int rid = (b*2048 + q0 + pat + 4*hi)*16 + h;
        pO[(size_t)rid*64 +      l31] = f2b(oacc[0][r]);
        pO[(size_t)rid*64 + 32 + l31] = f2b(oacc[1][r]);
    }
}

// ---------------- combine the two kv-halves ----------------
// idx = ((b*2048+q)*16 + h)*64 + d  ==  flat index of aob[(b*2048+q)*1024 + h*64 + d]
__global__ __launch_bounds__(256) void attn_merge(
    const u16* __restrict__ pO0, const u16* __restrict__ pO1,  // pO1 aliases aout (in-place)
    const float* __restrict__ pM, const float* __restrict__ pL,
    u16* __restrict__ aout)
{
    const int idx = blockIdx.x * 256 + threadIdx.x;
    const int rid = idx >> 6;
    const float m0 = pM[rid], m1 = pM[65536 + rid];
    const float l0 = pL[rid], l1 = pL[65536 + rid];
    const float mS = fmaxf(m0, m1);
    const float a0 = __expf(m0 - mS), a1 = __expf(m1 - mS);
    const float inv = 1.f / (l0*a0 + l1*a1);
    const float o0 = __uint_as_float((u32)pO0[idx] << 16);
    const float o1 = __uint_as_float((u32)pO1[idx] << 16);
    aout[idx] = f2b((o0*a0 + o1*a1) * inv);
}

extern "C" void kernel_launch(void* const* d_in, const int* in_sizes, int n_in,
                              void* d_out, int out_size, void* d_ws, size_t ws_size,
                              hipStream_t stream)
{
    (void)in_sizes; (void)n_in; (void)out_size; (void)ws_size;
    const float* x      = (const float*)d_in[0];
    const int*   mask   = (const int*)  d_in[1];
    const float* w_qkv  = (const float*)d_in[2];
    const float* w_proj = (const float*)d_in[3];
    const float* b_proj = (const float*)d_in[4];
    float* out = (float*)d_out;

    const int M = 4096;   // B*N
    const int C = 1024;

    u16* xb   = (u16*)d_ws;                    // M*C          (dead after gemm1 -> pO0)
    u16* wqb  = xb   + (size_t)M*C;            // 3C*C         (dead after gemm1 -> pM/pL)
    u16* wpb  = wqb  + (size_t)3*C*C;          // C*C
    u16* qkvb = wpb  + (size_t)C*C;            // M*3C
    u16* aob  = qkvb + (size_t)M*3*C;          // M*C          (pO1 / merge output)

    u16*   pO0 = xb;                 // 4096*1024 bf16 = 8 MB (xb region, free after gemm1)
    u16*   pO1 = aob;                // half-1 partial written in place
    float* pM  = (float*)wqb;        // 2*65536 f32
    float* pL  = pM + 2*65536;       // 2*65536 f32  (1 MB total, inside wqb's 6 MB)

    cvt_bf16<<<dim3((M*C/4   + 255)/256), 256, 0, stream>>>(x,      xb,  M*C/4);
    cvt_bf16<<<dim3((3*C*C/4 + 255)/256), 256, 0, stream>>>(w_qkv,  wqb, 3*C*C/4);
    cvt_bf16<<<dim3((C*C/4   + 255)/256), 256, 0, stream>>>(w_proj, wpb, C*C/4);

    gemm_bt<<<dim3(3*C/128, M/128), 256, 0, stream>>>(xb, wqb, qkvb, nullptr, nullptr, M, 3*C, C);
    attn_half<<<dim3(1024), 256, 0, stream>>>(qkvb, mask, pO0, pO1, pM, pL);
    attn_merge<<<dim3(4096*1024/256), 256, 0, stream>>>(pO0, pO1, pM, pL, aob);
    gemm_bt<<<dim3(C/128, M/128), 256, 0, stream>>>(aob, wpb, nullptr, out, b_proj, M, C, C);
}

// Round 5
// 172.929 us; speedup vs baseline: 1.0347x; 1.0347x over previous
//
#include <hip/hip_runtime.h>

typedef unsigned short u16;
typedef unsigned int   u32;
typedef unsigned long long u64;
typedef short  short8 __attribute__((ext_vector_type(8)));
typedef float  f32x4  __attribute__((ext_vector_type(4)));
typedef float  f32x16 __attribute__((ext_vector_type(16)));
typedef u16    u16x4  __attribute__((ext_vector_type(4)));

__device__ __forceinline__ u16 f2b(float f) {
    u32 u = __float_as_uint(f);
    u32 r = (u + 0x7fffu + ((u >> 16) & 1u)) >> 16;  // RNE to bf16
    return (u16)r;
}

__device__ __forceinline__ u32 cvtpk(float a, float b) {
    u32 r;
    asm("v_cvt_pk_bf16_f32 %0, %1, %2" : "=v"(r) : "v"(a), "v"(b));
    return r;  // lo = bf16(a), hi = bf16(b)
}

__device__ __forceinline__ void gload_lds16(const void* g, void* l) {
    __builtin_amdgcn_global_load_lds(
        (const __attribute__((address_space(1))) u32*)g,
        (__attribute__((address_space(3))) u32*)l,
        16, 0, 0);
}

// ---------------- fp32 -> bf16 cast ----------------
__global__ void cvt_bf16(const float* __restrict__ src, u16* __restrict__ dst, int n4) {
    int i = blockIdx.x * blockDim.x + threadIdx.x;
    if (i >= n4) return;
    float4 v = ((const float4*)src)[i];
    u16x4 r = { f2b(v.x), f2b(v.y), f2b(v.z), f2b(v.w) };
    ((u16x4*)dst)[i] = r;
}

// ---------------- C = A @ B^T (A:[M,K], B:[N,K], bf16 in, fp32 acc) ----------------
// (round-2 verified version, verbatim)
__global__ __launch_bounds__(256) void gemm_bt(
    const u16* __restrict__ A, const u16* __restrict__ Bm,
    u16* __restrict__ Cb, float* __restrict__ Cf, const float* __restrict__ bias,
    int M, int N, int K)
{
    __shared__ __align__(16) u16 As[128*32];
    __shared__ __align__(16) u16 Bs[128*32];
    const int t = threadIdx.x;
    const int w = t >> 6, lane = t & 63;
    const int l15 = lane & 15, lg = lane >> 4;
    const int m0 = blockIdx.y * 128, n0 = blockIdx.x * 128;
    const int wr = w >> 1, wc = w & 1;
    f32x4 acc[4][4] = {};

    for (int kt = 0; kt < K; kt += 32) {
        #pragma unroll
        for (int j = 0; j < 2; ++j) {
            const int c   = j*256 + t;
            const int row = c >> 2, colb = (c & 3) * 8;
            gload_lds16(&A [(size_t)(m0+row)*K + kt + colb], &As[(size_t)(j*256 + w*64)*8]);
            gload_lds16(&Bm[(size_t)(n0+row)*K + kt + colb], &Bs[(size_t)(j*256 + w*64)*8]);
        }
        __syncthreads();
        short8 af[4], bfr[4];
        #pragma unroll
        for (int mi = 0; mi < 4; ++mi)
            af[mi] = *(const short8*)&As[(wr*64 + mi*16 + l15)*32 + lg*8];
        #pragma unroll
        for (int ni = 0; ni < 4; ++ni)
            bfr[ni] = *(const short8*)&Bs[(wc*64 + ni*16 + l15)*32 + lg*8];
        #pragma unroll
        for (int mi = 0; mi < 4; ++mi)
            #pragma unroll
            for (int ni = 0; ni < 4; ++ni)
                acc[mi][ni] = __builtin_amdgcn_mfma_f32_16x16x32_bf16(af[mi], bfr[ni], acc[mi][ni], 0, 0, 0);
        __syncthreads();
    }

    #pragma unroll
    for (int mi = 0; mi < 4; ++mi) {
        #pragma unroll
        for (int ni = 0; ni < 4; ++ni) {
            const int row = m0 + wr*64 + mi*16 + lg*4;
            const int col = n0 + wc*64 + ni*16 + l15;
            if (Cb) {
                #pragma unroll
                for (int r = 0; r < 4; ++r)
                    Cb[(size_t)(row+r)*N + col] = f2b(acc[mi][ni][r]);
            } else {
                const float bv = bias ? bias[col] : 0.f;
                #pragma unroll
                for (int r = 0; r < 4; ++r)
                    Cf[(size_t)(row+r)*N + col] = acc[mi][ni][r] + bv;
            }
        }
    }
}

// ---------------- fused masked flash attention v4: double-buffered pipeline ----------------
// Round-2 math, restructured sync: Ks/Vt double-buffered, ONE raw s_barrier per tile,
// counted s_waitcnt vmcnt(3) (K-DMA for tile t+1 issued during tile t; V/mask prefetch
// stay in flight across the barrier). grid 512, 4 waves x 32 q-rows.
__global__ __launch_bounds__(256) void attn_v4(
    const u16* __restrict__ qkv,   // [B*N][3072] bf16
    const int* __restrict__ mask,  // [B*N]
    u16* __restrict__ aout)        // [B*N][1024] bf16
{
    __shared__ __align__(16) u16 Ks[2][64*64];   // [kv][d], chunk ^= kv&7
    __shared__ __align__(16) u16 Vt[2][64*64];   // [d][kv], chunk ^= (d^(d>>3))&7

    const int t = threadIdx.x, w = t >> 6, lane = t & 63;
    const int l31 = lane & 31, hi = lane >> 5;

    const int wid = ((blockIdx.x & 7) << 6) | (blockIdx.x >> 3);   // XCD-contiguous
    const int qt = wid & 15, h = (wid >> 4) & 15, b = wid >> 8;
    const int q0 = qt * 128 + w * 32;
    const int kvb = b * 2048;

    const size_t qrow = (size_t)(kvb + q0 + l31);
    short8 qf[4];
    #pragma unroll
    for (int i = 0; i < 4; ++i)
        qf[i] = *(const short8*)&qkv[qrow*3072 + h*64 + i*16 + hi*8];
    const int mq = mask[kvb + q0 + l31];

    float m_run = -3e38f, l_run = 0.f;
    f32x16 oacc[2] = {};

    // staging roles
    const int vrr = t >> 3, vc8 = t & 7;                 // V: rows vrr, vrr+32
    const int sc  = (lane & 7) ^ (lane >> 3);            // K source chunk swizzle
    const int kri = lane >> 3;

    // ---- prologue: stage tile 0, prefetch tile 1 ----
    short8 vnx0, vnx1;
    {
        const u16* p = qkv + (size_t)(kvb + vrr)*3072 + 2048 + h*64 + vc8*8;
        vnx0 = *(const short8*)p;
        vnx1 = *(const short8*)(p + (size_t)32*3072);
    }
    int mcur = mask[kvb + lane];
    #pragma unroll
    for (int pp = 0; pp < 2; ++pp) {
        const int kv = pp*32 + vrr;
        const int kvhi = kv >> 3, kvlo = kv & 7;
        const short8 v = pp ? vnx1 : vnx0;
        #pragma unroll
        for (int j = 0; j < 8; ++j)
            Vt[0][(vc8*8 + j)*64 + ((kvhi ^ ((j ^ vc8) & 7)) << 3) + kvlo] = (u16)v[j];
    }
    #pragma unroll
    for (int i = 0; i < 2; ++i)
        gload_lds16(&qkv[(size_t)(kvb + w*16 + i*8 + kri)*3072 + 1024 + h*64 + sc*8],
                    &Ks[0][(w*16 + i*8)*64]);
    __builtin_amdgcn_sched_barrier(0);
    {
        const u16* p = qkv + (size_t)(kvb + 64 + vrr)*3072 + 2048 + h*64 + vc8*8;
        vnx0 = *(const short8*)p;
        vnx1 = *(const short8*)(p + (size_t)32*3072);
    }
    asm volatile("s_waitcnt vmcnt(2) lgkmcnt(0)" ::: "memory");
    __builtin_amdgcn_s_barrier();
    __builtin_amdgcn_sched_barrier(0);

    for (int it = 0; it < 32; ++it) {
        u16* __restrict__ KsB = Ks[it & 1];
        u16* __restrict__ VtB = Vt[it & 1];
        u16* __restrict__ KsN = Ks[(it & 1) ^ 1];
        u16* __restrict__ VtN = Vt[(it & 1) ^ 1];
        const int tn1 = (it + 1 < 32 ? it + 1 : 31) * 64;   // clamped (last stage unused)
        const int tn2 = (it + 2 < 32 ? it + 2 : 31) * 64;

        // A: publish prefetched V (tile it+1) into back buffer (swizzled scalar writes)
        #pragma unroll
        for (int pp = 0; pp < 2; ++pp) {
            const int kv = pp*32 + vrr;
            const int kvhi = kv >> 3, kvlo = kv & 7;
            const short8 v = pp ? vnx1 : vnx0;
            #pragma unroll
            for (int j = 0; j < 8; ++j)
                VtN[(vc8*8 + j)*64 + ((kvhi ^ ((j ^ vc8) & 7)) << 3) + kvlo] = (u16)v[j];
        }
        // B: K DMA (tile it+1) into back buffer — must stay OLDEST in vmem queue
        #pragma unroll
        for (int i = 0; i < 2; ++i)
            gload_lds16(&qkv[(size_t)(kvb + tn1 + w*16 + i*8 + kri)*3072 + 1024 + h*64 + sc*8],
                        &KsN[(w*16 + i*8)*64]);
        __builtin_amdgcn_sched_barrier(0);
        // C: V prefetch (tile it+2) — stays in flight across the barrier
        {
            const u16* p = qkv + (size_t)(kvb + tn2 + vrr)*3072 + 2048 + h*64 + vc8*8;
            vnx0 = *(const short8*)p;
            vnx1 = *(const short8*)(p + (size_t)32*3072);
        }
        // D: mask prefetch (tile it+1)
        const int mnew = mask[kvb + tn1 + lane];
        // E: ballot for the CURRENT tile (mcur loaded one tile ago — wait is free)
        const u64 bal = __ballot(mcur != 0);
        const u32 mwA = (u32)bal, mwB = (u32)(bal >> 32);

        // ---- F: compute tile it (round-2 body, buffers KsB/VtB) ----
        f32x16 st0 = {}, st1 = {};
        #pragma unroll
        for (int kd = 0; kd < 4; ++kd) {
            const int c = (2*kd + hi) ^ (l31 & 7);
            short8 kf0 = *(const short8*)&KsB[ l31      *64 + c*8];
            short8 kf1 = *(const short8*)&KsB[(32 + l31)*64 + c*8];
            st0 = __builtin_amdgcn_mfma_f32_32x32x16_bf16(kf0, qf[kd], st0, 0, 0, 0);
            st1 = __builtin_amdgcn_mfma_f32_32x32x16_bf16(kf1, qf[kd], st1, 0, 0, 0);
        }

        const u32 km0 = (mq ? mwA : 0u) >> (hi*4);
        const u32 km1 = (mq ? mwB : 0u) >> (hi*4);
        #pragma unroll
        for (int r = 0; r < 16; ++r) {
            const int pat = (r & 3) + 8*(r >> 2);
            const float t0 = ((km0 >> pat) & 1u) ? 0.f : -3e38f;
            const float t1 = ((km1 >> pat) & 1u) ? 0.f : -3e38f;
            st0[r] = fmaf(st0[r], 0.125f, t0);
            st1[r] = fmaf(st1[r], 0.125f, t1);
        }

        float pm0 = -3e38f, pm1 = -3e38f, pm2 = -3e38f, pm3 = -3e38f;
        #pragma unroll
        for (int r = 0; r < 16; r += 4) {
            pm0 = fmaxf(pm0, fmaxf(st0[r],   st1[r]));
            pm1 = fmaxf(pm1, fmaxf(st0[r+1], st1[r+1]));
            pm2 = fmaxf(pm2, fmaxf(st0[r+2], st1[r+2]));
            pm3 = fmaxf(pm3, fmaxf(st0[r+3], st1[r+3]));
        }
        float pm = fmaxf(fmaxf(pm0, pm1), fmaxf(pm2, pm3));
        pm = fmaxf(pm, __shfl_xor(pm, 32));
        const float m_new = fmaxf(m_run, pm);
        const float alpha = __expf(m_run - m_new);
        float rs0 = 0.f, rs1 = 0.f;
        #pragma unroll
        for (int r = 0; r < 16; ++r) {
            const float p0 = __expf(st0[r] - m_new);
            const float p1 = __expf(st1[r] - m_new);
            st0[r] = p0; st1[r] = p1;
            rs0 += p0; rs1 += p1;
        }
        float rs = rs0 + rs1;
        rs += __shfl_xor(rs, 32);
        l_run = l_run * alpha + rs;
        m_run = m_new;

        u32 o_[16];
        #pragma unroll
        for (int m = 0; m < 8; ++m) {
            o_[m]     = cvtpk(st0[2*m], st0[2*m+1]);
            o_[8 + m] = cvtpk(st1[2*m], st1[2*m+1]);
        }

        #pragma unroll
        for (int r = 0; r < 16; ++r) {
            const int pat = (r & 3) + 8*(r >> 2);
            const float ar = __shfl(alpha, pat + 4*hi);
            oacc[0][r] *= ar; oacc[1][r] *= ar;
        }

        #pragma unroll
        for (int kk = 0; kk < 4; ++kk) {
            const int base = (kk >> 1)*8 + (kk & 1)*4;
            const u32 x0 = (u32)__shfl_xor((int)o_[base],   32);
            const u32 x1 = (u32)__shfl_xor((int)o_[base+1], 32);
            const u32 x2 = (u32)__shfl_xor((int)o_[base+2], 32);
            const u32 x3 = (u32)__shfl_xor((int)o_[base+3], 32);
            union { u32 u[4]; short8 s; } pa;
            pa.u[0] = hi ? x2 : o_[base];
            pa.u[1] = hi ? x3 : o_[base+1];
            pa.u[2] = hi ? o_[base+2] : x0;
            pa.u[3] = hi ? o_[base+3] : x1;
            #pragma unroll
            for (int dt = 0; dt < 2; ++dt) {
                const int d = dt*32 + l31;
                const int c = (2*kk + hi) ^ ((d ^ (d >> 3)) & 7);
                short8 vf = *(const short8*)&VtB[d*64 + c*8];
                oacc[dt] = __builtin_amdgcn_mfma_f32_32x32x16_bf16(pa.s, vf, oacc[dt], 0, 0, 0);
            }
        }

        mcur = mnew;
        // H/I: drain ONLY the 2 K-DMA ops (3 newer stay in flight), then raw barrier
        asm volatile("s_waitcnt vmcnt(3) lgkmcnt(0)" ::: "memory");
        __builtin_amdgcn_s_barrier();
        __builtin_amdgcn_sched_barrier(0);
    }

    // ---- epilogue ----
    const float inv = 1.f / l_run;
    #pragma unroll
    for (int r = 0; r < 16; ++r) {
        const int pat = (r & 3) + 8*(r >> 2);
        const float ir = __shfl(inv, pat + 4*hi);
        const size_t rowg = (size_t)(kvb + q0 + pat + 4*hi);
        aout[rowg*1024 + h*64 +      l31] = f2b(oacc[0][r] * ir);
        aout[rowg*1024 + h*64 + 32 + l31] = f2b(oacc[1][r] * ir);
    }
}

extern "C" void kernel_launch(void* const* d_in, const int* in_sizes, int n_in,
                              void* d_out, int out_size, void* d_ws, size_t ws_size,
                              hipStream_t stream)
{
    (void)in_sizes; (void)n_in; (void)out_size; (void)ws_size;
    const float* x      = (const float*)d_in[0];
    const int*   mask   = (const int*)  d_in[1];
    const float* w_qkv  = (const float*)d_in[2];
    const float* w_proj = (const float*)d_in[3];
    const float* b_proj = (const float*)d_in[4];
    float* out = (float*)d_out;

    const int M = 4096;   // B*N
    const int C = 1024;

    u16* xb   = (u16*)d_ws;                    // M*C
    u16* wqb  = xb   + (size_t)M*C;            // 3C*C
    u16* wpb  = wqb  + (size_t)3*C*C;          // C*C
    u16* qkvb = wpb  + (size_t)C*C;            // M*3C
    u16* aob  = qkvb + (size_t)M*3*C;          // M*C

    cvt_bf16<<<dim3((M*C/4   + 255)/256), 256, 0, stream>>>(x,      xb,  M*C/4);
    cvt_bf16<<<dim3((3*C*C/4 + 255)/256), 256, 0, stream>>>(w_qkv,  wqb, 3*C*C/4);
    cvt_bf16<<<dim3((C*C/4   + 255)/256), 256, 0, stream>>>(w_proj, wpb, C*C/4);

    gemm_bt<<<dim3(3*C/128, M/128), 256, 0, stream>>>(xb, wqb, qkvb, nullptr, nullptr, M, 3*C, C);
    attn_v4<<<dim3(512), 256, 0, stream>>>(qkvb, mask, aob);
    gemm_bt<<<dim3(C/128, M/128), 256, 0, stream>>>(aob, wpb, nullptr, out, b_proj, M, C, C);
}

// Round 7
// 158.308 us; speedup vs baseline: 1.1302x; 1.0924x over previous
//
#include <hip/hip_runtime.h>

typedef unsigned short u16;
typedef unsigned int   u32;
typedef unsigned long long u64;
typedef short  short8 __attribute__((ext_vector_type(8)));
typedef float  f32x4  __attribute__((ext_vector_type(4)));
typedef float  f32x16 __attribute__((ext_vector_type(16)));
typedef u16    u16x4  __attribute__((ext_vector_type(4)));

__device__ __forceinline__ u16 f2b(float f) {
    u32 u = __float_as_uint(f);
    u32 r = (u + 0x7fffu + ((u >> 16) & 1u)) >> 16;  // RNE to bf16
    return (u16)r;
}

__device__ __forceinline__ u32 cvtpk(float a, float b) {
    u32 r;
    asm("v_cvt_pk_bf16_f32 %0, %1, %2" : "=v"(r) : "v"(a), "v"(b));
    return r;  // lo = bf16(a), hi = bf16(b)
}

__device__ __forceinline__ float ex2(float x) {   // 2^x, native v_exp_f32
    float r;
    asm("v_exp_f32 %0, %1" : "=v"(r) : "v"(x));
    return r;
}

__device__ __forceinline__ void gload_lds16(const void* g, void* l) {
    __builtin_amdgcn_global_load_lds(
        (const __attribute__((address_space(1))) u32*)g,
        (__attribute__((address_space(3))) u32*)l,
        16, 0, 0);
}

// ---------------- fp32 -> bf16 cast ----------------
__global__ void cvt_bf16(const float* __restrict__ src, u16* __restrict__ dst, int n4) {
    int i = blockIdx.x * blockDim.x + threadIdx.x;
    if (i >= n4) return;
    float4 v = ((const float4*)src)[i];
    u16x4 r = { f2b(v.x), f2b(v.y), f2b(v.z), f2b(v.w) };
    ((u16x4*)dst)[i] = r;
}

// ---------------- C = A @ B^T (A:[M,K], B:[N,K], bf16 in, fp32 acc) ----------------
// (round-2 verified version, verbatim)
__global__ __launch_bounds__(256) void gemm_bt(
    const u16* __restrict__ A, const u16* __restrict__ Bm,
    u16* __restrict__ Cb, float* __restrict__ Cf, const float* __restrict__ bias,
    int M, int N, int K)
{
    __shared__ __align__(16) u16 As[128*32];
    __shared__ __align__(16) u16 Bs[128*32];
    const int t = threadIdx.x;
    const int w = t >> 6, lane = t & 63;
    const int l15 = lane & 15, lg = lane >> 4;
    const int m0 = blockIdx.y * 128, n0 = blockIdx.x * 128;
    const int wr = w >> 1, wc = w & 1;
    f32x4 acc[4][4] = {};

    for (int kt = 0; kt < K; kt += 32) {
        #pragma unroll
        for (int j = 0; j < 2; ++j) {
            const int c   = j*256 + t;
            const int row = c >> 2, colb = (c & 3) * 8;
            gload_lds16(&A [(size_t)(m0+row)*K + kt + colb], &As[(size_t)(j*256 + w*64)*8]);
            gload_lds16(&Bm[(size_t)(n0+row)*K + kt + colb], &Bs[(size_t)(j*256 + w*64)*8]);
        }
        __syncthreads();
        short8 af[4], bfr[4];
        #pragma unroll
        for (int mi = 0; mi < 4; ++mi)
            af[mi] = *(const short8*)&As[(wr*64 + mi*16 + l15)*32 + lg*8];
        #pragma unroll
        for (int ni = 0; ni < 4; ++ni)
            bfr[ni] = *(const short8*)&Bs[(wc*64 + ni*16 + l15)*32 + lg*8];
        #pragma unroll
        for (int mi = 0; mi < 4; ++mi)
            #pragma unroll
            for (int ni = 0; ni < 4; ++ni)
                acc[mi][ni] = __builtin_amdgcn_mfma_f32_16x16x32_bf16(af[mi], bfr[ni], acc[mi][ni], 0, 0, 0);
        __syncthreads();
    }

    #pragma unroll
    for (int mi = 0; mi < 4; ++mi) {
        #pragma unroll
        for (int ni = 0; ni < 4; ++ni) {
            const int row = m0 + wr*64 + mi*16 + lg*4;
            const int col = n0 + wc*64 + ni*16 + l15;
            if (Cb) {
                #pragma unroll
                for (int r = 0; r < 4; ++r)
                    Cb[(size_t)(row+r)*N + col] = f2b(acc[mi][ni][r]);
            } else {
                const float bv = bias ? bias[col] : 0.f;
                #pragma unroll
                for (int r = 0; r < 4; ++r)
                    Cf[(size_t)(row+r)*N + col] = acc[mi][ni][r] + bv;
            }
        }
    }
}

// ---------------- fused masked flash attention v5: VALU diet ----------------
// Round-2 verified skeleton (staging/swizzles/sync/PV identical). Changes:
//  (1) kv-mask applied as an MFMA bias k-step (A = mask? 0 : -3.39e38, B = e0),
//      replacing the 32-element bit-extract/select chain.
//  (2) defer-max: rescale only when tile max exceeds m+11.5 (log2 units).
//  (3) softmax in exp2 space: p = ex2(fmaf(s, qs2, -m2)), one fmaf + v_exp per elem.
__global__ __launch_bounds__(256) void attn_v5(
    const u16* __restrict__ qkv,   // [B*N][3072] bf16
    const int* __restrict__ mask,  // [B*N]
    u16* __restrict__ aout)        // [B*N][1024] bf16
{
    __shared__ __align__(16) u16 Ks[64*64];   // [kv][d], chunk ^= kv&7
    __shared__ __align__(16) u16 Vt[64*64];   // [d][kv], chunk ^= (d^(d>>3))&7

    const int t = threadIdx.x, w = t >> 6, lane = t & 63;
    const int l31 = lane & 31, hi = lane >> 5;

    const int wid = ((blockIdx.x & 7) << 6) | (blockIdx.x >> 3);   // XCD-contiguous
    const int qt = wid & 15, h = (wid >> 4) & 15, b = wid >> 8;
    const int q0 = qt * 128 + w * 32;

    const size_t qrow = (size_t)(b*2048 + q0 + l31);
    short8 qf[4];
    #pragma unroll
    for (int i = 0; i < 4; ++i)
        qf[i] = *(const short8*)&qkv[qrow*3072 + h*64 + i*16 + hi*8];
    const int mq = mask[b*2048 + q0 + l31];
    const float qs2 = mq ? 0.18033688011f : 0.f;   // 0.125 * log2(e); 0 -> uniform row

    // constant B-frag for the bias k-step: Q_ext[q][k] = (k==0) -> 1.0
    union { u32 u[4]; short8 s; } qe;
    qe.u[0] = hi ? 0u : 0x3F80u;   // bf16 1.0 in k-slot 0 (hi==0 lanes own k=0..7)
    qe.u[1] = 0; qe.u[2] = 0; qe.u[3] = 0;

    float m2 = -3e38f, l_run = 0.f;    // m2 in log2-scaled units
    f32x16 oacc[2] = {};

    const int vrr = t >> 3, vc8 = t & 7;  // V stage role: rows vrr, vrr+32
    short8 vreg0 = *(const short8*)&qkv[(size_t)(b*2048 +      vrr)*3072 + 2048 + h*64 + vc8*8];
    short8 vreg1 = *(const short8*)&qkv[(size_t)(b*2048 + 32 + vrr)*3072 + 2048 + h*64 + vc8*8];

    for (int kv0 = 0; kv0 < 2048; kv0 += 64) {
        __syncthreads();   // previous tile's compute done; Ks/Vt writable
        // ---- V^T swizzled scalar writes (conflict-free) ----
        #pragma unroll
        for (int p = 0; p < 2; ++p) {
            const int kv = p*32 + vrr;
            const int kvhi = kv >> 3, kvlo = kv & 7;
            const short8 v = p ? vreg1 : vreg0;
            #pragma unroll
            for (int j = 0; j < 8; ++j)
                Vt[(vc8*8 + j)*64 + ((kvhi ^ ((j ^ vc8) & 7)) << 3) + kvlo] = (u16)v[j];
        }
        // ---- K stage: global_load_lds, source pre-swizzled (chunk ^ row&7) ----
        #pragma unroll
        for (int i = 0; i < 2; ++i) {
            const int row = w*16 + i*8 + (lane >> 3);
            const int sc  = (lane & 7) ^ (lane >> 3);
            gload_lds16(&qkv[(size_t)(b*2048 + kv0 + row)*3072 + 1024 + h*64 + sc*8],
                        &Ks[(w*16 + i*8)*64]);
        }
        const u64 bal = __ballot(mask[b*2048 + kv0 + lane] != 0);
        const u32 mwA = (u32)bal, mwB = (u32)(bal >> 32);
        __syncthreads();   // staged data visible

        // prefetch next tile's V (hides HBM under compute)
        if (kv0 + 64 < 2048) {
            vreg0 = *(const short8*)&qkv[(size_t)(b*2048 + kv0+64 + vrr)*3072 + 2048 + h*64 + vc8*8];
            vreg1 = *(const short8*)&qkv[(size_t)(b*2048 + kv0+96 + vrr)*3072 + 2048 + h*64 + vc8*8];
        }

        // ---- S^T: two 32x32 subtiles, 4 k-steps each ----
        f32x16 st0 = {}, st1 = {};
        #pragma unroll
        for (int kd = 0; kd < 4; ++kd) {
            const int c = (2*kd + hi) ^ (l31 & 7);
            short8 kf0 = *(const short8*)&Ks[ l31      *64 + c*8];
            short8 kf1 = *(const short8*)&Ks[(32 + l31)*64 + c*8];
            st0 = __builtin_amdgcn_mfma_f32_32x32x16_bf16(kf0, qf[kd], st0, 0, 0, 0);
            st1 = __builtin_amdgcn_mfma_f32_32x32x16_bf16(kf1, qf[kd], st1, 0, 0, 0);
        }
        // ---- kv-mask as bias k-step: st[kv][q] += (mask[kv] ? 0 : -3.39e38) ----
        {
            union { u32 u[4]; short8 s; } ba0, ba1;
            ba0.u[0] = (((mwA >> l31) & 1u) | (u32)hi) ? 0u : 0xFF7Fu;  // bf16 -3.3895e38
            ba1.u[0] = (((mwB >> l31) & 1u) | (u32)hi) ? 0u : 0xFF7Fu;
            ba0.u[1] = 0; ba0.u[2] = 0; ba0.u[3] = 0;
            ba1.u[1] = 0; ba1.u[2] = 0; ba1.u[3] = 0;
            st0 = __builtin_amdgcn_mfma_f32_32x32x16_bf16(ba0.s, qe.s, st0, 0, 0, 0);
            st1 = __builtin_amdgcn_mfma_f32_32x32x16_bf16(ba1.s, qe.s, st1, 0, 0, 0);
        }

        // ---- raw tile max ----
        float pm0 = -3e38f, pm1 = -3e38f, pm2 = -3e38f, pm3 = -3e38f;
        #pragma unroll
        for (int r = 0; r < 16; r += 4) {
            pm0 = fmaxf(pm0, fmaxf(st0[r],   st1[r]));
            pm1 = fmaxf(pm1, fmaxf(st0[r+1], st1[r+1]));
            pm2 = fmaxf(pm2, fmaxf(st0[r+2], st1[r+2]));
            pm3 = fmaxf(pm3, fmaxf(st0[r+3], st1[r+3]));
        }
        const float pmx = fmaxf(fmaxf(pm0, pm1), fmaxf(pm2, pm3));

        // ---- defer-max: full rescale only when max grew past THR (=8/ln2) ----
        if (__any(fmaf(pmx, qs2, -m2) > 11.5f)) {
            float pml = pmx * qs2;
            pml = fmaxf(pml, __shfl_xor(pml, 32));
            const float m_new = fmaxf(m2, pml);
            const float alpha = ex2(m2 - m_new);
            l_run *= alpha;
            #pragma unroll
            for (int r = 0; r < 16; ++r) {
                const int pat = (r & 3) + 8*(r >> 2);
                const float ar = __shfl(alpha, pat + 4*hi);
                oacc[0][r] *= ar; oacc[1][r] *= ar;
            }
            m2 = m_new;
        }

        // ---- p = exp2(s*qs2 - m2): one fmaf + one native v_exp per element ----
        const float nm = -m2;
        float rs = 0.f;
        #pragma unroll
        for (int r = 0; r < 16; ++r) {
            const float p0 = ex2(fmaf(st0[r], qs2, nm));
            const float p1 = ex2(fmaf(st1[r], qs2, nm));
            st0[r] = p0; st1[r] = p1;
            rs += p0 + p1;
        }
        rs += __shfl_xor(rs, 32);
        l_run += rs;

        // ---- pack P to bf16 (in-register) ----
        u32 o_[16];
        #pragma unroll
        for (int m = 0; m < 8; ++m) {
            o_[m]     = cvtpk(st0[2*m], st0[2*m+1]);
            o_[8 + m] = cvtpk(st1[2*m], st1[2*m+1]);
        }

        // ---- PV: O += P @ V ----
        #pragma unroll
        for (int kk = 0; kk < 4; ++kk) {
            const int base = (kk >> 1)*8 + (kk & 1)*4;
            const u32 x0 = (u32)__shfl_xor((int)o_[base],   32);
            const u32 x1 = (u32)__shfl_xor((int)o_[base+1], 32);
            const u32 x2 = (u32)__shfl_xor((int)o_[base+2], 32);
            const u32 x3 = (u32)__shfl_xor((int)o_[base+3], 32);
            union { u32 u[4]; short8 s; } pa;
            pa.u[0] = hi ? x2 : o_[base];
            pa.u[1] = hi ? x3 : o_[base+1];
            pa.u[2] = hi ? o_[base+2] : x0;
            pa.u[3] = hi ? o_[base+3] : x1;
            #pragma unroll
            for (int dt = 0; dt < 2; ++dt) {
                const int d = dt*32 + l31;
                const int c = (2*kk + hi) ^ ((d ^ (d >> 3)) & 7);
                short8 vf = *(const short8*)&Vt[d*64 + c*8];
                oacc[dt] = __builtin_amdgcn_mfma_f32_32x32x16_bf16(pa.s, vf, oacc[dt], 0, 0, 0);
            }
        }
    }

    // ---- epilogue ----
    const float inv = 1.f / l_run;
    #pragma unroll
    for (int r = 0; r < 16; ++r) {
        const int pat = (r & 3) + 8*(r >> 2);
        const float ir = __shfl(inv, pat + 4*hi);
        const size_t rowg = (size_t)(b*2048 + q0 + pat + 4*hi);
        aout[rowg*1024 + h*64 +      l31] = f2b(oacc[0][r] * ir);
        aout[rowg*1024 + h*64 + 32 + l31] = f2b(oacc[1][r] * ir);
    }
}

extern "C" void kernel_launch(void* const* d_in, const int* in_sizes, int n_in,
                              void* d_out, int out_size, void* d_ws, size_t ws_size,
                              hipStream_t stream)
{
    (void)in_sizes; (void)n_in; (void)out_size; (void)ws_size;
    const float* x      = (const float*)d_in[0];
    const int*   mask   = (const int*)  d_in[1];
    const float* w_qkv  = (const float*)d_in[2];
    const float* w_proj = (const float*)d_in[3];
    const float* b_proj = (const float*)d_in[4];
    float* out = (float*)d_out;

    const int M = 4096;   // B*N
    const int C = 1024;

    u16* xb   = (u16*)d_ws;                    // M*C
    u16* wqb  = xb   + (size_t)M*C;            // 3C*C
    u16* wpb  = wqb  + (size_t)3*C*C;          // C*C
    u16* qkvb = wpb  + (size_t)C*C;            // M*3C
    u16* aob  = qkvb + (size_t)M*3*C;          // M*C

    cvt_bf16<<<dim3((M*C/4   + 255)/256), 256, 0, stream>>>(x,      xb,  M*C/4);
    cvt_bf16<<<dim3((3*C*C/4 + 255)/256), 256, 0, stream>>>(w_qkv,  wqb, 3*C*C/4);
    cvt_bf16<<<dim3((C*C/4   + 255)/256), 256, 0, stream>>>(w_proj, wpb, C*C/4);

    gemm_bt<<<dim3(3*C/128, M/128), 256, 0, stream>>>(xb, wqb, qkvb, nullptr, nullptr, M, 3*C, C);
    attn_v5<<<dim3(512), 256, 0, stream>>>(qkvb, mask, aob);
    gemm_bt<<<dim3(C/128, M/128), 256, 0, stream>>>(aob, wpb, nullptr, out, b_proj, M, C, C);
}

// Round 8
// 149.819 us; speedup vs baseline: 1.1943x; 1.0567x over previous
//
#include <hip/hip_runtime.h>

typedef unsigned short u16;
typedef unsigned int   u32;
typedef unsigned long long u64;
typedef short  short8 __attribute__((ext_vector_type(8)));
typedef float  f32x4  __attribute__((ext_vector_type(4)));
typedef float  f32x16 __attribute__((ext_vector_type(16)));
typedef u16    u16x4  __attribute__((ext_vector_type(4)));

__device__ __forceinline__ u16 f2b(float f) {
    u32 u = __float_as_uint(f);
    u32 r = (u + 0x7fffu + ((u >> 16) & 1u)) >> 16;  // RNE to bf16
    return (u16)r;
}

__device__ __forceinline__ u32 cvtpk(float a, float b) {
    u32 r;
    asm("v_cvt_pk_bf16_f32 %0, %1, %2" : "=v"(r) : "v"(a), "v"(b));
    return r;  // lo = bf16(a), hi = bf16(b)
}

__device__ __forceinline__ float ex2(float x) {   // 2^x, native v_exp_f32
    float r;
    asm("v_exp_f32 %0, %1" : "=v"(r) : "v"(x));
    return r;
}

__device__ __forceinline__ void gload_lds16(const void* g, void* l) {
    __builtin_amdgcn_global_load_lds(
        (const __attribute__((address_space(1))) u32*)g,
        (__attribute__((address_space(3))) u32*)l,
        16, 0, 0);
}

// ---------------- fused fp32 -> bf16 casts (one launch for x, w_qkv, w_proj) ----------------
#define N4X 1048576   // 4096*1024/4
#define N4Q  786432   // 3*1024*1024/4
#define N4P  262144   // 1024*1024/4
__global__ __launch_bounds__(256) void cvt_all(
    const float* __restrict__ x, const float* __restrict__ wq, const float* __restrict__ wp,
    u16* __restrict__ xb, u16* __restrict__ wqb, u16* __restrict__ wpb)
{
    const int i = blockIdx.x * 256 + threadIdx.x;   // grid covers N4X+N4Q+N4P exactly
    const float* src; u16* dst; int j;
    if (i < N4X)            { src = x;  dst = xb;  j = i; }
    else if (i < N4X + N4Q) { src = wq; dst = wqb; j = i - N4X; }
    else                    { src = wp; dst = wpb; j = i - N4X - N4Q; }
    float4 v = ((const float4*)src)[j];
    u16x4 r = { f2b(v.x), f2b(v.y), f2b(v.z), f2b(v.w) };
    ((u16x4*)dst)[j] = r;
}

// ---------------- C = A @ B^T, 128x128 tile (round-2 verified, verbatim) ----------------
__global__ __launch_bounds__(256) void gemm_bt(
    const u16* __restrict__ A, const u16* __restrict__ Bm,
    u16* __restrict__ Cb, float* __restrict__ Cf, const float* __restrict__ bias,
    int M, int N, int K)
{
    __shared__ __align__(16) u16 As[128*32];
    __shared__ __align__(16) u16 Bs[128*32];
    const int t = threadIdx.x;
    const int w = t >> 6, lane = t & 63;
    const int l15 = lane & 15, lg = lane >> 4;
    const int m0 = blockIdx.y * 128, n0 = blockIdx.x * 128;
    const int wr = w >> 1, wc = w & 1;
    f32x4 acc[4][4] = {};

    for (int kt = 0; kt < K; kt += 32) {
        #pragma unroll
        for (int j = 0; j < 2; ++j) {
            const int c   = j*256 + t;
            const int row = c >> 2, colb = (c & 3) * 8;
            gload_lds16(&A [(size_t)(m0+row)*K + kt + colb], &As[(size_t)(j*256 + w*64)*8]);
            gload_lds16(&Bm[(size_t)(n0+row)*K + kt + colb], &Bs[(size_t)(j*256 + w*64)*8]);
        }
        __syncthreads();
        short8 af[4], bfr[4];
        #pragma unroll
        for (int mi = 0; mi < 4; ++mi)
            af[mi] = *(const short8*)&As[(wr*64 + mi*16 + l15)*32 + lg*8];
        #pragma unroll
        for (int ni = 0; ni < 4; ++ni)
            bfr[ni] = *(const short8*)&Bs[(wc*64 + ni*16 + l15)*32 + lg*8];
        #pragma unroll
        for (int mi = 0; mi < 4; ++mi)
            #pragma unroll
            for (int ni = 0; ni < 4; ++ni)
                acc[mi][ni] = __builtin_amdgcn_mfma_f32_16x16x32_bf16(af[mi], bfr[ni], acc[mi][ni], 0, 0, 0);
        __syncthreads();
    }

    #pragma unroll
    for (int mi = 0; mi < 4; ++mi) {
        #pragma unroll
        for (int ni = 0; ni < 4; ++ni) {
            const int row = m0 + wr*64 + mi*16 + lg*4;
            const int col = n0 + wc*64 + ni*16 + l15;
            if (Cb) {
                #pragma unroll
                for (int r = 0; r < 4; ++r)
                    Cb[(size_t)(row+r)*N + col] = f2b(acc[mi][ni][r]);
            } else {
                const float bv = bias ? bias[col] : 0.f;
                #pragma unroll
                for (int r = 0; r < 4; ++r)
                    Cf[(size_t)(row+r)*N + col] = acc[mi][ni][r] + bv;
            }
        }
    }
}

// ---------------- C = A @ B^T, 64x128 tile (for small-N proj: 2x the blocks) ----------------
// BM=64, BN=128, BK=32; 4 waves in 2x2, each wave 32(M) x 64(N) = 2x4 frags.
__global__ __launch_bounds__(256) void gemm_bt64(
    const u16* __restrict__ A, const u16* __restrict__ Bm,
    float* __restrict__ Cf, const float* __restrict__ bias,
    int M, int N, int K)
{
    __shared__ __align__(16) u16 As[64*32];
    __shared__ __align__(16) u16 Bs[128*32];
    const int t = threadIdx.x;
    const int w = t >> 6, lane = t & 63;
    const int l15 = lane & 15, lg = lane >> 4;
    const int m0 = blockIdx.y * 64, n0 = blockIdx.x * 128;
    const int wr = w >> 1, wc = w & 1;
    f32x4 acc[2][4] = {};

    for (int kt = 0; kt < K; kt += 32) {
        // A tile 64x32: 1 gload/thread; wave w covers rows w*16 .. w*16+15
        gload_lds16(&A[(size_t)(m0 + w*16 + (lane >> 2))*K + kt + (lane & 3)*8],
                    &As[(size_t)w*512]);
        // B tile 128x32: 2 gloads/thread (identical to 128x128 version)
        #pragma unroll
        for (int j = 0; j < 2; ++j) {
            const int c   = j*256 + t;
            const int row = c >> 2, colb = (c & 3) * 8;
            gload_lds16(&Bm[(size_t)(n0+row)*K + kt + colb], &Bs[(size_t)(j*256 + w*64)*8]);
        }
        __syncthreads();
        short8 af[2], bfr[4];
        #pragma unroll
        for (int mi = 0; mi < 2; ++mi)
            af[mi] = *(const short8*)&As[(wr*32 + mi*16 + l15)*32 + lg*8];
        #pragma unroll
        for (int ni = 0; ni < 4; ++ni)
            bfr[ni] = *(const short8*)&Bs[(wc*64 + ni*16 + l15)*32 + lg*8];
        #pragma unroll
        for (int mi = 0; mi < 2; ++mi)
            #pragma unroll
            for (int ni = 0; ni < 4; ++ni)
                acc[mi][ni] = __builtin_amdgcn_mfma_f32_16x16x32_bf16(af[mi], bfr[ni], acc[mi][ni], 0, 0, 0);
        __syncthreads();
    }

    #pragma unroll
    for (int mi = 0; mi < 2; ++mi) {
        #pragma unroll
        for (int ni = 0; ni < 4; ++ni) {
            const int row = m0 + wr*32 + mi*16 + lg*4;
            const int col = n0 + wc*64 + ni*16 + l15;
            const float bv = bias ? bias[col] : 0.f;
            #pragma unroll
            for (int r = 0; r < 4; ++r)
                Cf[(size_t)(row+r)*N + col] = acc[mi][ni][r] + bv;
        }
    }
}

// ---------------- fused masked flash attention v5 (round-7 verified, verbatim) ----------------
__global__ __launch_bounds__(256) void attn_v5(
    const u16* __restrict__ qkv,   // [B*N][3072] bf16
    const int* __restrict__ mask,  // [B*N]
    u16* __restrict__ aout)        // [B*N][1024] bf16
{
    __shared__ __align__(16) u16 Ks[64*64];   // [kv][d], chunk ^= kv&7
    __shared__ __align__(16) u16 Vt[64*64];   // [d][kv], chunk ^= (d^(d>>3))&7

    const int t = threadIdx.x, w = t >> 6, lane = t & 63;
    const int l31 = lane & 31, hi = lane >> 5;

    const int wid = ((blockIdx.x & 7) << 6) | (blockIdx.x >> 3);   // XCD-contiguous
    const int qt = wid & 15, h = (wid >> 4) & 15, b = wid >> 8;
    const int q0 = qt * 128 + w * 32;

    const size_t qrow = (size_t)(b*2048 + q0 + l31);
    short8 qf[4];
    #pragma unroll
    for (int i = 0; i < 4; ++i)
        qf[i] = *(const short8*)&qkv[qrow*3072 + h*64 + i*16 + hi*8];
    const int mq = mask[b*2048 + q0 + l31];
    const float qs2 = mq ? 0.18033688011f : 0.f;   // 0.125 * log2(e); 0 -> uniform row

    union { u32 u[4]; short8 s; } qe;
    qe.u[0] = hi ? 0u : 0x3F80u;   // bf16 1.0 in k-slot 0
    qe.u[1] = 0; qe.u[2] = 0; qe.u[3] = 0;

    float m2 = -3e38f, l_run = 0.f;    // m2 in log2-scaled units
    f32x16 oacc[2] = {};

    const int vrr = t >> 3, vc8 = t & 7;
    short8 vreg0 = *(const short8*)&qkv[(size_t)(b*2048 +      vrr)*3072 + 2048 + h*64 + vc8*8];
    short8 vreg1 = *(const short8*)&qkv[(size_t)(b*2048 + 32 + vrr)*3072 + 2048 + h*64 + vc8*8];

    for (int kv0 = 0; kv0 < 2048; kv0 += 64) {
        __syncthreads();
        #pragma unroll
        for (int p = 0; p < 2; ++p) {
            const int kv = p*32 + vrr;
            const int kvhi = kv >> 3, kvlo = kv & 7;
            const short8 v = p ? vreg1 : vreg0;
            #pragma unroll
            for (int j = 0; j < 8; ++j)
                Vt[(vc8*8 + j)*64 + ((kvhi ^ ((j ^ vc8) & 7)) << 3) + kvlo] = (u16)v[j];
        }
        #pragma unroll
        for (int i = 0; i < 2; ++i) {
            const int row = w*16 + i*8 + (lane >> 3);
            const int sc  = (lane & 7) ^ (lane >> 3);
            gload_lds16(&qkv[(size_t)(b*2048 + kv0 + row)*3072 + 1024 + h*64 + sc*8],
                        &Ks[(w*16 + i*8)*64]);
        }
        const u64 bal = __ballot(mask[b*2048 + kv0 + lane] != 0);
        const u32 mwA = (u32)bal, mwB = (u32)(bal >> 32);
        __syncthreads();

        if (kv0 + 64 < 2048) {
            vreg0 = *(const short8*)&qkv[(size_t)(b*2048 + kv0+64 + vrr)*3072 + 2048 + h*64 + vc8*8];
            vreg1 = *(const short8*)&qkv[(size_t)(b*2048 + kv0+96 + vrr)*3072 + 2048 + h*64 + vc8*8];
        }

        f32x16 st0 = {}, st1 = {};
        #pragma unroll
        for (int kd = 0; kd < 4; ++kd) {
            const int c = (2*kd + hi) ^ (l31 & 7);
            short8 kf0 = *(const short8*)&Ks[ l31      *64 + c*8];
            short8 kf1 = *(const short8*)&Ks[(32 + l31)*64 + c*8];
            st0 = __builtin_amdgcn_mfma_f32_32x32x16_bf16(kf0, qf[kd], st0, 0, 0, 0);
            st1 = __builtin_amdgcn_mfma_f32_32x32x16_bf16(kf1, qf[kd], st1, 0, 0, 0);
        }
        {
            union { u32 u[4]; short8 s; } ba0, ba1;
            ba0.u[0] = (((mwA >> l31) & 1u) | (u32)hi) ? 0u : 0xFF7Fu;  // bf16 -3.3895e38
            ba1.u[0] = (((mwB >> l31) & 1u) | (u32)hi) ? 0u : 0xFF7Fu;
            ba0.u[1] = 0; ba0.u[2] = 0; ba0.u[3] = 0;
            ba1.u[1] = 0; ba1.u[2] = 0; ba1.u[3] = 0;
            st0 = __builtin_amdgcn_mfma_f32_32x32x16_bf16(ba0.s, qe.s, st0, 0, 0, 0);
            st1 = __builtin_amdgcn_mfma_f32_32x32x16_bf16(ba1.s, qe.s, st1, 0, 0, 0);
        }

        float pm0 = -3e38f, pm1 = -3e38f, pm2 = -3e38f, pm3 = -3e38f;
        #pragma unroll
        for (int r = 0; r < 16; r += 4) {
            pm0 = fmaxf(pm0, fmaxf(st0[r],   st1[r]));
            pm1 = fmaxf(pm1, fmaxf(st0[r+1], st1[r+1]));
            pm2 = fmaxf(pm2, fmaxf(st0[r+2], st1[r+2]));
            pm3 = fmaxf(pm3, fmaxf(st0[r+3], st1[r+3]));
        }
        const float pmx = fmaxf(fmaxf(pm0, pm1), fmaxf(pm2, pm3));

        if (__any(fmaf(pmx, qs2, -m2) > 11.5f)) {
            float pml = pmx * qs2;
            pml = fmaxf(pml, __shfl_xor(pml, 32));
            const float m_new = fmaxf(m2, pml);
            const float alpha = ex2(m2 - m_new);
            l_run *= alpha;
            #pragma unroll
            for (int r = 0; r < 16; ++r) {
                const int pat = (r & 3) + 8*(r >> 2);
                const float ar = __shfl(alpha, pat + 4*hi);
                oacc[0][r] *= ar; oacc[1][r] *= ar;
            }
            m2 = m_new;
        }

        const float nm = -m2;
        float rs = 0.f;
        #pragma unroll
        for (int r = 0; r < 16; ++r) {
            const float p0 = ex2(fmaf(st0[r], qs2, nm));
            const float p1 = ex2(fmaf(st1[r], qs2, nm));
            st0[r] = p0; st1[r] = p1;
            rs += p0 + p1;
        }
        rs += __shfl_xor(rs, 32);
        l_run += rs;

        u32 o_[16];
        #pragma unroll
        for (int m = 0; m < 8; ++m) {
            o_[m]     = cvtpk(st0[2*m], st0[2*m+1]);
            o_[8 + m] = cvtpk(st1[2*m], st1[2*m+1]);
        }

        #pragma unroll
        for (int kk = 0; kk < 4; ++kk) {
            const int base = (kk >> 1)*8 + (kk & 1)*4;
            const u32 x0 = (u32)__shfl_xor((int)o_[base],   32);
            const u32 x1 = (u32)__shfl_xor((int)o_[base+1], 32);
            const u32 x2 = (u32)__shfl_xor((int)o_[base+2], 32);
            const u32 x3 = (u32)__shfl_xor((int)o_[base+3], 32);
            union { u32 u[4]; short8 s; } pa;
            pa.u[0] = hi ? x2 : o_[base];
            pa.u[1] = hi ? x3 : o_[base+1];
            pa.u[2] = hi ? o_[base+2] : x0;
            pa.u[3] = hi ? o_[base+3] : x1;
            #pragma unroll
            for (int dt = 0; dt < 2; ++dt) {
                const int d = dt*32 + l31;
                const int c = (2*kk + hi) ^ ((d ^ (d >> 3)) & 7);
                short8 vf = *(const short8*)&Vt[d*64 + c*8];
                oacc[dt] = __builtin_amdgcn_mfma_f32_32x32x16_bf16(pa.s, vf, oacc[dt], 0, 0, 0);
            }
        }
    }

    const float inv = 1.f / l_run;
    #pragma unroll
    for (int r = 0; r < 16; ++r) {
        const int pat = (r & 3) + 8*(r >> 2);
        const float ir = __shfl(inv, pat + 4*hi);
        const size_t rowg = (size_t)(b*2048 + q0 + pat + 4*hi);
        aout[rowg*1024 + h*64 +      l31] = f2b(oacc[0][r] * ir);
        aout[rowg*1024 + h*64 + 32 + l31] = f2b(oacc[1][r] * ir);
    }
}

extern "C" void kernel_launch(void* const* d_in, const int* in_sizes, int n_in,
                              void* d_out, int out_size, void* d_ws, size_t ws_size,
                              hipStream_t stream)
{
    (void)in_sizes; (void)n_in; (void)out_size; (void)ws_size;
    const float* x      = (const float*)d_in[0];
    const int*   mask   = (const int*)  d_in[1];
    const float* w_qkv  = (const float*)d_in[2];
    const float* w_proj = (const float*)d_in[3];
    const float* b_proj = (const float*)d_in[4];
    float* out = (float*)d_out;

    const int M = 4096;   // B*N
    const int C = 1024;

    u16* xb   = (u16*)d_ws;                    // M*C
    u16* wqb  = xb   + (size_t)M*C;            // 3C*C
    u16* wpb  = wqb  + (size_t)3*C*C;          // C*C
    u16* qkvb = wpb  + (size_t)C*C;            // M*3C
    u16* aob  = qkvb + (size_t)M*3*C;          // M*C

    cvt_all<<<dim3((N4X + N4Q + N4P) / 256), 256, 0, stream>>>(x, w_qkv, w_proj, xb, wqb, wpb);

    gemm_bt<<<dim3(3*C/128, M/128), 256, 0, stream>>>(xb, wqb, qkvb, nullptr, nullptr, M, 3*C, C);
    attn_v5<<<dim3(512), 256, 0, stream>>>(qkvb, mask, aob);
    gemm_bt64<<<dim3(C/128, M/64), 256, 0, stream>>>(aob, wpb, out, b_proj, M, C, C);
}

// Round 9
// 142.358 us; speedup vs baseline: 1.2569x; 1.0524x over previous
//
#include <hip/hip_runtime.h>

typedef unsigned short u16;
typedef unsigned int   u32;
typedef unsigned long long u64;
typedef short  short8 __attribute__((ext_vector_type(8)));
typedef float  f32x2  __attribute__((ext_vector_type(2)));
typedef float  f32x4  __attribute__((ext_vector_type(4)));
typedef float  f32x16 __attribute__((ext_vector_type(16)));
typedef u16    u16x4  __attribute__((ext_vector_type(4)));

__device__ __forceinline__ u16 f2b(float f) {
    u32 u = __float_as_uint(f);
    u32 r = (u + 0x7fffu + ((u >> 16) & 1u)) >> 16;  // RNE to bf16
    return (u16)r;
}

__device__ __forceinline__ u32 cvtpk(float a, float b) {
    u32 r;
    asm("v_cvt_pk_bf16_f32 %0, %1, %2" : "=v"(r) : "v"(a), "v"(b));
    return r;  // lo = bf16(a), hi = bf16(b)
}

__device__ __forceinline__ float ex2(float x) {   // 2^x, native v_exp_f32
    float r;
    asm("v_exp_f32 %0, %1" : "=v"(r) : "v"(x));
    return r;
}

__device__ __forceinline__ f32x2 pkfma(f32x2 a, f32x2 b, f32x2 c) {  // a*b+c per half
    f32x2 d;
    asm("v_pk_fma_f32 %0, %1, %2, %3" : "=v"(d) : "v"(a), "v"(b), "v"(c));
    return d;
}

// swap a's upper 32 lanes with c's lower 32 lanes:
// new_a = {a.row0, c.row0(from lane^32)}, new_c = {a.row1(from lane^32), c.row1}
__device__ __forceinline__ void pl32swap(u32& a, u32& c) {
    asm("v_permlane32_swap_b32 %0, %1" : "+v"(a), "+v"(c));
}

__device__ __forceinline__ void gload_lds16(const void* g, void* l) {
    __builtin_amdgcn_global_load_lds(
        (const __attribute__((address_space(1))) u32*)g,
        (__attribute__((address_space(3))) u32*)l,
        16, 0, 0);
}

// ---------------- fused fp32 -> bf16 casts (one launch for x, w_qkv, w_proj) ----------------
#define N4X 1048576   // 4096*1024/4
#define N4Q  786432   // 3*1024*1024/4
#define N4P  262144   // 1024*1024/4
__global__ __launch_bounds__(256) void cvt_all(
    const float* __restrict__ x, const float* __restrict__ wq, const float* __restrict__ wp,
    u16* __restrict__ xb, u16* __restrict__ wqb, u16* __restrict__ wpb)
{
    const int i = blockIdx.x * 256 + threadIdx.x;   // grid covers N4X+N4Q+N4P exactly
    const float* src; u16* dst; int j;
    if (i < N4X)            { src = x;  dst = xb;  j = i; }
    else if (i < N4X + N4Q) { src = wq; dst = wqb; j = i - N4X; }
    else                    { src = wp; dst = wpb; j = i - N4X - N4Q; }
    float4 v = ((const float4*)src)[j];
    u16x4 r = { f2b(v.x), f2b(v.y), f2b(v.z), f2b(v.w) };
    ((u16x4*)dst)[j] = r;
}

// ---------------- C = A @ B^T, 128x128 tile (round-2 verified, verbatim) ----------------
__global__ __launch_bounds__(256) void gemm_bt(
    const u16* __restrict__ A, const u16* __restrict__ Bm,
    u16* __restrict__ Cb, float* __restrict__ Cf, const float* __restrict__ bias,
    int M, int N, int K)
{
    __shared__ __align__(16) u16 As[128*32];
    __shared__ __align__(16) u16 Bs[128*32];
    const int t = threadIdx.x;
    const int w = t >> 6, lane = t & 63;
    const int l15 = lane & 15, lg = lane >> 4;
    const int m0 = blockIdx.y * 128, n0 = blockIdx.x * 128;
    const int wr = w >> 1, wc = w & 1;
    f32x4 acc[4][4] = {};

    for (int kt = 0; kt < K; kt += 32) {
        #pragma unroll
        for (int j = 0; j < 2; ++j) {
            const int c   = j*256 + t;
            const int row = c >> 2, colb = (c & 3) * 8;
            gload_lds16(&A [(size_t)(m0+row)*K + kt + colb], &As[(size_t)(j*256 + w*64)*8]);
            gload_lds16(&Bm[(size_t)(n0+row)*K + kt + colb], &Bs[(size_t)(j*256 + w*64)*8]);
        }
        __syncthreads();
        short8 af[4], bfr[4];
        #pragma unroll
        for (int mi = 0; mi < 4; ++mi)
            af[mi] = *(const short8*)&As[(wr*64 + mi*16 + l15)*32 + lg*8];
        #pragma unroll
        for (int ni = 0; ni < 4; ++ni)
            bfr[ni] = *(const short8*)&Bs[(wc*64 + ni*16 + l15)*32 + lg*8];
        #pragma unroll
        for (int mi = 0; mi < 4; ++mi)
            #pragma unroll
            for (int ni = 0; ni < 4; ++ni)
                acc[mi][ni] = __builtin_amdgcn_mfma_f32_16x16x32_bf16(af[mi], bfr[ni], acc[mi][ni], 0, 0, 0);
        __syncthreads();
    }

    #pragma unroll
    for (int mi = 0; mi < 4; ++mi) {
        #pragma unroll
        for (int ni = 0; ni < 4; ++ni) {
            const int row = m0 + wr*64 + mi*16 + lg*4;
            const int col = n0 + wc*64 + ni*16 + l15;
            if (Cb) {
                #pragma unroll
                for (int r = 0; r < 4; ++r)
                    Cb[(size_t)(row+r)*N + col] = f2b(acc[mi][ni][r]);
            } else {
                const float bv = bias ? bias[col] : 0.f;
                #pragma unroll
                for (int r = 0; r < 4; ++r)
                    Cf[(size_t)(row+r)*N + col] = acc[mi][ni][r] + bv;
            }
        }
    }
}

// ---------------- C = A @ B^T, 64x128 tile (round-8 verified, verbatim) ----------------
__global__ __launch_bounds__(256) void gemm_bt64(
    const u16* __restrict__ A, const u16* __restrict__ Bm,
    float* __restrict__ Cf, const float* __restrict__ bias,
    int M, int N, int K)
{
    __shared__ __align__(16) u16 As[64*32];
    __shared__ __align__(16) u16 Bs[128*32];
    const int t = threadIdx.x;
    const int w = t >> 6, lane = t & 63;
    const int l15 = lane & 15, lg = lane >> 4;
    const int m0 = blockIdx.y * 64, n0 = blockIdx.x * 128;
    const int wr = w >> 1, wc = w & 1;
    f32x4 acc[2][4] = {};

    for (int kt = 0; kt < K; kt += 32) {
        gload_lds16(&A[(size_t)(m0 + w*16 + (lane >> 2))*K + kt + (lane & 3)*8],
                    &As[(size_t)w*512]);
        #pragma unroll
        for (int j = 0; j < 2; ++j) {
            const int c   = j*256 + t;
            const int row = c >> 2, colb = (c & 3) * 8;
            gload_lds16(&Bm[(size_t)(n0+row)*K + kt + colb], &Bs[(size_t)(j*256 + w*64)*8]);
        }
        __syncthreads();
        short8 af[2], bfr[4];
        #pragma unroll
        for (int mi = 0; mi < 2; ++mi)
            af[mi] = *(const short8*)&As[(wr*32 + mi*16 + l15)*32 + lg*8];
        #pragma unroll
        for (int ni = 0; ni < 4; ++ni)
            bfr[ni] = *(const short8*)&Bs[(wc*64 + ni*16 + l15)*32 + lg*8];
        #pragma unroll
        for (int mi = 0; mi < 2; ++mi)
            #pragma unroll
            for (int ni = 0; ni < 4; ++ni)
                acc[mi][ni] = __builtin_amdgcn_mfma_f32_16x16x32_bf16(af[mi], bfr[ni], acc[mi][ni], 0, 0, 0);
        __syncthreads();
    }

    #pragma unroll
    for (int mi = 0; mi < 2; ++mi) {
        #pragma unroll
        for (int ni = 0; ni < 4; ++ni) {
            const int row = m0 + wr*32 + mi*16 + lg*4;
            const int col = n0 + wc*64 + ni*16 + l15;
            const float bv = bias ? bias[col] : 0.f;
            #pragma unroll
            for (int r = 0; r < 4; ++r)
                Cf[(size_t)(row+r)*N + col] = acc[mi][ni][r] + bv;
        }
    }
}

// ---------------- fused masked flash attention v6 ----------------
// Round-7 verified skeleton. Changes (math-identical):
//  (a) PV half-swap via v_permlane32_swap_b32 (8 swaps replace 16 bpermute + 16 cndmask)
//  (b) pre-exp fmaf as v_pk_fma_f32 pairs; exp fused straight into cvtpk
//  (c) s_setprio(1) around both MFMA clusters (T5)
__global__ __launch_bounds__(256) void attn_v6(
    const u16* __restrict__ qkv,   // [B*N][3072] bf16
    const int* __restrict__ mask,  // [B*N]
    u16* __restrict__ aout)        // [B*N][1024] bf16
{
    __shared__ __align__(16) u16 Ks[64*64];   // [kv][d], chunk ^= kv&7
    __shared__ __align__(16) u16 Vt[64*64];   // [d][kv], chunk ^= (d^(d>>3))&7

    const int t = threadIdx.x, w = t >> 6, lane = t & 63;
    const int l31 = lane & 31, hi = lane >> 5;

    const int wid = ((blockIdx.x & 7) << 6) | (blockIdx.x >> 3);   // XCD-contiguous
    const int qt = wid & 15, h = (wid >> 4) & 15, b = wid >> 8;
    const int q0 = qt * 128 + w * 32;

    const size_t qrow = (size_t)(b*2048 + q0 + l31);
    short8 qf[4];
    #pragma unroll
    for (int i = 0; i < 4; ++i)
        qf[i] = *(const short8*)&qkv[qrow*3072 + h*64 + i*16 + hi*8];
    const int mq = mask[b*2048 + q0 + l31];
    const float qs2 = mq ? 0.18033688011f : 0.f;   // 0.125 * log2(e); 0 -> uniform row

    union { u32 u[4]; short8 s; } qe;
    qe.u[0] = hi ? 0u : 0x3F80u;   // bf16 1.0 in k-slot 0
    qe.u[1] = 0; qe.u[2] = 0; qe.u[3] = 0;

    float m2 = -3e38f, l_run = 0.f;    // m2 in log2-scaled units
    f32x16 oacc[2] = {};

    const int vrr = t >> 3, vc8 = t & 7;
    short8 vreg0 = *(const short8*)&qkv[(size_t)(b*2048 +      vrr)*3072 + 2048 + h*64 + vc8*8];
    short8 vreg1 = *(const short8*)&qkv[(size_t)(b*2048 + 32 + vrr)*3072 + 2048 + h*64 + vc8*8];

    for (int kv0 = 0; kv0 < 2048; kv0 += 64) {
        __syncthreads();
        #pragma unroll
        for (int p = 0; p < 2; ++p) {
            const int kv = p*32 + vrr;
            const int kvhi = kv >> 3, kvlo = kv & 7;
            const short8 v = p ? vreg1 : vreg0;
            #pragma unroll
            for (int j = 0; j < 8; ++j)
                Vt[(vc8*8 + j)*64 + ((kvhi ^ ((j ^ vc8) & 7)) << 3) + kvlo] = (u16)v[j];
        }
        #pragma unroll
        for (int i = 0; i < 2; ++i) {
            const int row = w*16 + i*8 + (lane >> 3);
            const int sc  = (lane & 7) ^ (lane >> 3);
            gload_lds16(&qkv[(size_t)(b*2048 + kv0 + row)*3072 + 1024 + h*64 + sc*8],
                        &Ks[(w*16 + i*8)*64]);
        }
        const u64 bal = __ballot(mask[b*2048 + kv0 + lane] != 0);
        const u32 mwA = (u32)bal, mwB = (u32)(bal >> 32);
        __syncthreads();

        if (kv0 + 64 < 2048) {
            vreg0 = *(const short8*)&qkv[(size_t)(b*2048 + kv0+64 + vrr)*3072 + 2048 + h*64 + vc8*8];
            vreg1 = *(const short8*)&qkv[(size_t)(b*2048 + kv0+96 + vrr)*3072 + 2048 + h*64 + vc8*8];
        }

        // ---- S^T: two 32x32 subtiles + mask-bias k-step ----
        f32x16 st0 = {}, st1 = {};
        __builtin_amdgcn_s_setprio(1);
        #pragma unroll
        for (int kd = 0; kd < 4; ++kd) {
            const int c = (2*kd + hi) ^ (l31 & 7);
            short8 kf0 = *(const short8*)&Ks[ l31      *64 + c*8];
            short8 kf1 = *(const short8*)&Ks[(32 + l31)*64 + c*8];
            st0 = __builtin_amdgcn_mfma_f32_32x32x16_bf16(kf0, qf[kd], st0, 0, 0, 0);
            st1 = __builtin_amdgcn_mfma_f32_32x32x16_bf16(kf1, qf[kd], st1, 0, 0, 0);
        }
        {
            union { u32 u[4]; short8 s; } ba0, ba1;
            ba0.u[0] = (((mwA >> l31) & 1u) | (u32)hi) ? 0u : 0xFF7Fu;  // bf16 -3.3895e38
            ba1.u[0] = (((mwB >> l31) & 1u) | (u32)hi) ? 0u : 0xFF7Fu;
            ba0.u[1] = 0; ba0.u[2] = 0; ba0.u[3] = 0;
            ba1.u[1] = 0; ba1.u[2] = 0; ba1.u[3] = 0;
            st0 = __builtin_amdgcn_mfma_f32_32x32x16_bf16(ba0.s, qe.s, st0, 0, 0, 0);
            st1 = __builtin_amdgcn_mfma_f32_32x32x16_bf16(ba1.s, qe.s, st1, 0, 0, 0);
        }
        __builtin_amdgcn_s_setprio(0);

        // ---- raw tile max ----
        float pm0 = -3e38f, pm1 = -3e38f, pm2 = -3e38f, pm3 = -3e38f;
        #pragma unroll
        for (int r = 0; r < 16; r += 4) {
            pm0 = fmaxf(pm0, fmaxf(st0[r],   st1[r]));
            pm1 = fmaxf(pm1, fmaxf(st0[r+1], st1[r+1]));
            pm2 = fmaxf(pm2, fmaxf(st0[r+2], st1[r+2]));
            pm3 = fmaxf(pm3, fmaxf(st0[r+3], st1[r+3]));
        }
        const float pmx = fmaxf(fmaxf(pm0, pm1), fmaxf(pm2, pm3));

        // ---- defer-max: full rescale only when max grew past THR ----
        if (__any(fmaf(pmx, qs2, -m2) > 11.5f)) {
            float pml = pmx * qs2;
            pml = fmaxf(pml, __shfl_xor(pml, 32));
            const float m_new = fmaxf(m2, pml);
            const float alpha = ex2(m2 - m_new);
            l_run *= alpha;
            #pragma unroll
            for (int r = 0; r < 16; ++r) {
                const int pat = (r & 3) + 8*(r >> 2);
                const float ar = __shfl(alpha, pat + 4*hi);
                oacc[0][r] *= ar; oacc[1][r] *= ar;
            }
            m2 = m_new;
        }

        // ---- p = exp2(pk_fma(st, qs2, -m2)), fused into bf16 pack ----
        const float nm = -m2;
        const f32x2 qv = { qs2, qs2 };
        const f32x2 nv = { nm, nm };
        float rs0 = 0.f, rs1 = 0.f;
        u32 o_[16];
        #pragma unroll
        for (int i = 0; i < 8; ++i) {
            const f32x2 d0 = pkfma(__builtin_shufflevector(st0, st0, -1, -1) , qv, nv);
            (void)d0;
            break;
        }
        #pragma unroll
        for (int i = 0; i < 8; ++i) {
            f32x2 s0p = { st0[2*i], st0[2*i+1] };
            f32x2 s1p = { st1[2*i], st1[2*i+1] };
            const f32x2 d0 = pkfma(s0p, qv, nv);
            const f32x2 d1 = pkfma(s1p, qv, nv);
            const float p0 = ex2(d0.x), p1 = ex2(d0.y);
            const float p2 = ex2(d1.x), p3 = ex2(d1.y);
            o_[i]     = cvtpk(p0, p1);
            o_[8 + i] = cvtpk(p2, p3);
            rs0 += p0 + p1;
            rs1 += p2 + p3;
        }
        float rs = rs0 + rs1;
        rs += __shfl_xor(rs, 32);
        l_run += rs;

        // ---- PV: O += P @ V (half-swap via permlane32_swap) ----
        __builtin_amdgcn_s_setprio(1);
        #pragma unroll
        for (int kk = 0; kk < 4; ++kk) {
            const int base = (kk >> 1)*8 + (kk & 1)*4;
            u32 a0 = o_[base],   c0 = o_[base+2];
            u32 a1 = o_[base+1], c1 = o_[base+3];
            pl32swap(a0, c0);
            pl32swap(a1, c1);
            union { u32 u[4]; short8 s; } pa;
            pa.u[0] = a0; pa.u[1] = a1; pa.u[2] = c0; pa.u[3] = c1;
            #pragma unroll
            for (int dt = 0; dt < 2; ++dt) {
                const int d = dt*32 + l31;
                const int c = (2*kk + hi) ^ ((d ^ (d >> 3)) & 7);
                short8 vf = *(const short8*)&Vt[d*64 + c*8];
                oacc[dt] = __builtin_amdgcn_mfma_f32_32x32x16_bf16(pa.s, vf, oacc[dt], 0, 0, 0);
            }
        }
        __builtin_amdgcn_s_setprio(0);
    }

    // ---- epilogue ----
    const float inv = 1.f / l_run;
    #pragma unroll
    for (int r = 0; r < 16; ++r) {
        const int pat = (r & 3) + 8*(r >> 2);
        const float ir = __shfl(inv, pat + 4*hi);
        const size_t rowg = (size_t)(b*2048 + q0 + pat + 4*hi);
        aout[rowg*1024 + h*64 +      l31] = f2b(oacc[0][r] * ir);
        aout[rowg*1024 + h*64 + 32 + l31] = f2b(oacc[1][r] * ir);
    }
}

extern "C" void kernel_launch(void* const* d_in, const int* in_sizes, int n_in,
                              void* d_out, int out_size, void* d_ws, size_t ws_size,
                              hipStream_t stream)
{
    (void)in_sizes; (void)n_in; (void)out_size; (void)ws_size;
    const float* x      = (const float*)d_in[0];
    const int*   mask   = (const int*)  d_in[1];
    const float* w_qkv  = (const float*)d_in[2];
    const float* w_proj = (const float*)d_in[3];
    const float* b_proj = (const float*)d_in[4];
    float* out = (float*)d_out;

    const int M = 4096;   // B*N
    const int C = 1024;

    u16* xb   = (u16*)d_ws;                    // M*C
    u16* wqb  = xb   + (size_t)M*C;            // 3C*C
    u16* wpb  = wqb  + (size_t)3*C*C;          // C*C
    u16* qkvb = wpb  + (size_t)C*C;            // M*3C
    u16* aob  = qkvb + (size_t)M*3*C;          // M*C

    cvt_all<<<dim3((N4X + N4Q + N4P) / 256), 256, 0, stream>>>(x, w_qkv, w_proj, xb, wqb, wpb);

    gemm_bt<<<dim3(3*C/128, M/128), 256, 0, stream>>>(xb, wqb, qkvb, nullptr, nullptr, M, 3*C, C);
    attn_v6<<<dim3(512), 256, 0, stream>>>(qkvb, mask, aob);
    gemm_bt64<<<dim3(C/128, M/64), 256, 0, stream>>>(aob, wpb, out, b_proj, M, C, C);
}